// Round 4
// baseline (1301.443 us; speedup 1.0000x reference)
//
#include <hip/hip_runtime.h>
#include <hip/hip_bf16.h>

#define IN_F 4096
#define OUT_F 11008

typedef __bf16 bf16_t;
typedef bf16_t bf16x8 __attribute__((ext_vector_type(8)));
typedef float f32x4 __attribute__((ext_vector_type(4)));
typedef unsigned int u32;

// ============================ pass 1a: x f32 -> bf16 ============================
__global__ __launch_bounds__(256) void cvt_x_kernel(const float* __restrict__ x,
                                                    bf16_t* __restrict__ xb) {
    size_t i = ((size_t)blockIdx.x * 256 + threadIdx.x) * 8;
    f32x4 v0 = *(const f32x4*)(x + i);
    f32x4 v1 = *(const f32x4*)(x + i + 4);
    bf16x8 h;
    h[0]=(bf16_t)v0[0]; h[1]=(bf16_t)v0[1]; h[2]=(bf16_t)v0[2]; h[3]=(bf16_t)v0[3];
    h[4]=(bf16_t)v1[0]; h[5]=(bf16_t)v1[1]; h[6]=(bf16_t)v1[2]; h[7]=(bf16_t)v1[3];
    *(bf16x8*)(xb + i) = h;
}

// ============ pass 1b: dequant qweight -> Wt[n][k] bf16 (B^T layout) ============
__global__ __launch_bounds__(256) void dequant_kernel(const int* __restrict__ qweight,
                                                      const float* __restrict__ scales,
                                                      const int* __restrict__ qzeros,
                                                      bf16_t* __restrict__ wt) {
    const int n   = blockIdx.x * 256 + threadIdx.x;
    const int kw0 = blockIdx.y * 4;
    const int g   = kw0 >> 4;
    const float s  = scales[(size_t)g * OUT_F + n];
    const int   zw = qzeros[(size_t)g * (OUT_F / 8) + (n >> 3)];
    const float nsz = -s * (float)(((zw >> ((n & 7) * 4)) & 0xF) + 1);
    bf16_t* dst = wt + (size_t)n * IN_F + kw0 * 8;
    #pragma unroll
    for (int j = 0; j < 4; ++j) {
        const int w = qweight[(size_t)(kw0 + j) * OUT_F + n];
        bf16x8 h;
        #pragma unroll
        for (int b = 0; b < 8; ++b)
            h[b] = (bf16_t)fmaf((float)((w >> (4 * b)) & 0xF), s, nsz);
        *(bf16x8*)(dst + j * 8) = h;
    }
}

// ================== pass 2: 256x256 8-phase bf16 B^T GEMM ==================
// R3: ds_reads software-pipelined one phase ahead of their consuming MFMA;
// counted vmcnt moved to end of ph3/ph7 so boundary prefetches are legal.
// Per-phase read issue: 4/8/0/12/4/8/0/12 (was 16/0/8/0) -> DS overlaps MFMA.

#define NI (IN_F / 128)   // 32 iterations, 64 K-tiles

__global__ __launch_bounds__(512, 2) void gemm_8ph(const bf16_t* __restrict__ A,
                                                   const bf16_t* __restrict__ B,
                                                   float* __restrict__ C) {
    __shared__ __align__(16) bf16_t smemA[2 * 2 * 128 * 64];   // 64 KiB
    __shared__ __align__(16) bf16_t smemB[2 * 2 * 128 * 64];   // 64 KiB

    const int tid  = threadIdx.x;
    const int lane = tid & 63;
    const int wid  = tid >> 6;      // 0..7
    const int wr   = wid >> 2;      // 0..1  (M half)
    const int wc   = wid & 3;       // 0..3  (N quarter)

    // bijective XCD swizzle: nwg = 1376 = 8*172
    const int bid = blockIdx.x;
    const int swz = (bid & 7) * 172 + (bid >> 3);
    const int bx = swz % 43;
    const int by = swz / 43;
    const int m0 = by * 256;
    const int n0 = bx * 256;

    // staging map: linear LDS slot -> inverse-swizzled global position
    int lr0, kb0, lr1, kb1;
    {
        int L0 = tid * 16;
        int p0 = L0 ^ (((L0 >> 7) & 7) << 4);
        lr0 = p0 >> 7; kb0 = (p0 & 127) >> 1;
        int L1 = (512 + tid) * 16;
        int p1 = L1 ^ (((L1 >> 7) & 7) << 4);
        lr1 = p1 >> 7; kb1 = (p1 & 127) >> 1;
    }

    // fragment-read swizzled column byte offsets within a 128B row
    const int xm = (lane & 7) << 4;
    const int arow = lane & 15;
    int colk[2];
    #pragma unroll
    for (int ks = 0; ks < 2; ++ks)
        colk[ks] = ((ks * 64) + ((lane >> 4) * 16)) ^ xm;

#define STAGE(smem, buf, half, src, rbase, koff)                                           \
    do {                                                                                   \
        const bf16_t* g0_ = (src) + (size_t)((rbase) + lr0) * IN_F + (koff) + kb0;         \
        __builtin_amdgcn_global_load_lds(                                                  \
            (const __attribute__((address_space(1))) u32*)g0_,                             \
            (__attribute__((address_space(3))) u32*)((char*)(smem) + (buf) * 32768 +       \
                                                     (half) * 16384 + wid * 1024),         \
            16, 0, 0);                                                                     \
        const bf16_t* g1_ = (src) + (size_t)((rbase) + lr1) * IN_F + (koff) + kb1;         \
        __builtin_amdgcn_global_load_lds(                                                  \
            (const __attribute__((address_space(1))) u32*)g1_,                             \
            (__attribute__((address_space(3))) u32*)((char*)(smem) + (buf) * 32768 +       \
                                                     (half) * 16384 + 8192 + wid * 1024),  \
            16, 0, 0);                                                                     \
    } while (0)

#define STAGE_A(buf, half, koff) STAGE(smemA, buf, half, A, m0 + (half) * 128, koff)
#define STAGE_B(buf, half, koff) STAGE(smemB, buf, half, B, n0 + (half) * 128, koff)

// 8 ds_read_b128 -> dst[8] : A fragments (4 m-tiles x 2 k-slices)
#define LOAD_A_FRAGS(dst, buf, mbase)                                                      \
    _Pragma("unroll") for (int mm = 0; mm < 4; ++mm)                                       \
    _Pragma("unroll") for (int ks = 0; ks < 2; ++ks)                                       \
        dst[mm * 2 + ks] = *(const bf16x8*)((const char*)smemA + (buf) * 32768 +           \
            wr * 16384 + (((mbase) + mm) * 16 + arow) * 128 + colk[ks]);

// 4 ds_read_b128 -> dst[4] : B pair fragments (2 n-tiles x 2 k-slices), P in {0,1}
#define LOAD_B_PAIR(dst, buf, P)                                                           \
    _Pragma("unroll") for (int nn = 0; nn < 2; ++nn)                                       \
    _Pragma("unroll") for (int ks = 0; ks < 2; ++ks)                                       \
        dst[nn * 2 + ks] = *(const bf16x8*)((const char*)smemB + (buf) * 32768 +           \
            (wc >> 1) * 16384 + ((wc & 1) * 64 + ((P) * 2 + nn) * 16 + arow) * 128 +       \
            colk[ks]);

// 16 MFMA: one quadrant (4 m x 2 n x 2 ks)
#define MFMA_Q(aArr, bArr, mbase, nbase)                                                   \
    __builtin_amdgcn_s_setprio(1);                                                         \
    _Pragma("unroll") for (int mm = 0; mm < 4; ++mm)                                       \
    _Pragma("unroll") for (int nn = 0; nn < 2; ++nn)                                       \
    _Pragma("unroll") for (int ks = 0; ks < 2; ++ks)                                       \
        acc[(mbase) + mm][(nbase) + nn] = __builtin_amdgcn_mfma_f32_16x16x32_bf16(         \
            aArr[mm * 2 + ks], bArr[nn * 2 + ks], acc[(mbase) + mm][(nbase) + nn],         \
            0, 0, 0);                                                                      \
    __builtin_amdgcn_s_setprio(0);

#define BAR() __builtin_amdgcn_s_barrier()
#define VMCNT4() asm volatile("s_waitcnt vmcnt(4)" ::: "memory")
#define VMCNT0() asm volatile("s_waitcnt vmcnt(0)" ::: "memory")

    f32x4 acc[8][4];
    #pragma unroll
    for (int m = 0; m < 8; ++m)
        #pragma unroll
        for (int n = 0; n < 4; ++n)
            acc[m][n] = (f32x4)0.0f;

    bf16x8 aM0[8], aM1[8], b01[4], b23[4];

    // prologue: stage T0 fully + B(T1) + A(T1)h0 (7 half-tiles = 14 loads)
    STAGE_B(0, 0, 0);  STAGE_B(0, 1, 0);
    STAGE_A(0, 0, 0);  STAGE_A(0, 1, 0);
    STAGE_B(1, 0, 64); STAGE_B(1, 1, 64);
    STAGE_A(1, 0, 64);
    asm volatile("s_waitcnt vmcnt(6)" ::: "memory");   // T0's 8 loads landed
    BAR();
    LOAD_A_FRAGS(aM0, 0, 0);       // r1: ph1 fragments (issued one phase ahead)
    LOAD_B_PAIR(b01, 0, 0);

    for (int i = 0; i < NI; ++i) {
        const int  kc = i * 128;        // T0 in buf0; T1 = kc+64 in buf1
        const int  kn = kc + 128;       // T0+2 in buf0; T0+3 = kc+192 in buf1
        const bool nl = (i + 1 < NI);

        // ---- ph1: MFMA(M0,N01,buf0); prefetch r2(b23); stage A-h1(T1)
        LOAD_B_PAIR(b23, 0, 1);
        STAGE_A(1, 1, kc + 64);
        BAR();
        MFMA_Q(aM0, b01, 0, 0);
        BAR();
        // ---- ph2: MFMA(M0,N23); prefetch r3(aM1); stage B-h0(T0+2)
        LOAD_A_FRAGS(aM1, 0, 4);
        if (nl) STAGE_B(0, 0, kn);
        BAR();
        MFMA_Q(aM0, b23, 0, 2);
        BAR();
        // ---- ph3: MFMA(M1,N01); stage B-h1(T0+2); counted wait -> T1 confirmed
        if (nl) STAGE_B(0, 1, kn);
        BAR();
        MFMA_Q(aM1, b01, 4, 0);
        if (nl) VMCNT4(); else VMCNT0();
        BAR();
        // ---- ph4: MFMA(M1,N23); prefetch r5(aM0+b01, buf1); stage A-h0(T0+2)
        LOAD_A_FRAGS(aM0, 1, 0);
        LOAD_B_PAIR(b01, 1, 0);
        if (nl) STAGE_A(0, 0, kn);
        BAR();
        MFMA_Q(aM1, b23, 4, 2);
        BAR();
        // ---- ph5: MFMA(M0,N01,buf1); prefetch r6(b23); stage A-h1(T0+2)
        LOAD_B_PAIR(b23, 1, 1);
        if (nl) STAGE_A(0, 1, kn);
        BAR();
        MFMA_Q(aM0, b01, 0, 0);
        BAR();
        // ---- ph6: MFMA(M0,N23); prefetch r7(aM1); stage B-h0(T0+3)
        LOAD_A_FRAGS(aM1, 1, 4);
        if (nl) STAGE_B(1, 0, kc + 192);
        BAR();
        MFMA_Q(aM0, b23, 0, 2);
        BAR();
        // ---- ph7: MFMA(M1,N01); stage B-h1(T0+3); counted wait -> T0+2 confirmed
        if (nl) STAGE_B(1, 1, kc + 192);
        BAR();
        MFMA_Q(aM1, b01, 4, 0);
        if (nl) VMCNT4();
        BAR();
        // ---- ph8: MFMA(M1,N23); prefetch r1'(aM0+b01, buf0); stage A-h0(T0+3)
        if (nl) {
            LOAD_A_FRAGS(aM0, 0, 0);
            LOAD_B_PAIR(b01, 0, 0);
            STAGE_A(1, 0, kc + 192);
        }
        BAR();
        MFMA_Q(aM1, b23, 4, 2);
        BAR();
    }

    // epilogue: C/D layout col = lane&15, row = (lane>>4)*4 + r
    const int cn  = lane & 15;
    const int cr4 = (lane >> 4) * 4;
    #pragma unroll
    for (int m = 0; m < 8; ++m) {
        #pragma unroll
        for (int r = 0; r < 4; ++r) {
            const int grow = m0 + wr * 128 + m * 16 + cr4 + r;
            float* orow = C + (size_t)grow * OUT_F + n0 + wc * 64 + cn;
            #pragma unroll
            for (int n = 0; n < 4; ++n)
                orow[n * 16] = acc[m][n][r];
        }
    }
}

// ===================== fallback: fused kernel (R0 structure) =====================
#define BMf 128
#define BNf 128
#define BKf 32
#define LDPF 40

__global__ __launch_bounds__(256, 2) void gptq_gemm_fused(
    const float* __restrict__ x, const int* __restrict__ qweight,
    const float* __restrict__ scales, const int* __restrict__ qzeros,
    float* __restrict__ out)
{
    __shared__ bf16_t As[BMf * LDPF];
    __shared__ bf16_t Bs[BNf * LDPF];
    const int tid = threadIdx.x, lane = tid & 63, wid = tid >> 6;
    const int wr = wid >> 1, wc = wid & 1;
    const int m0 = blockIdx.y * BMf, n0 = blockIdx.x * BNf;
    const int a_row = tid >> 2, a_slot = tid & 3;
    const int b_k8l = tid >> 7, b_n = tid & 127;

    f32x4 acc[4][4];
    #pragma unroll
    for (int i = 0; i < 4; ++i)
        #pragma unroll
        for (int j = 0; j < 4; ++j) acc[i][j] = (f32x4)0.0f;

    for (int kt = 0; kt < IN_F / BKf; ++kt) {
        const int k0 = kt * BKf;
        const int g  = k0 >> 7;
        __syncthreads();
        #pragma unroll
        for (int p = 0; p < 2; ++p) {
            const int row = a_row + p * 64;
            const float* src = x + (size_t)(m0 + row) * IN_F + k0 + a_slot * 8;
            f32x4 v0 = *(const f32x4*)src;
            f32x4 v1 = *(const f32x4*)(src + 4);
            bf16x8 h;
            h[0]=(bf16_t)v0[0]; h[1]=(bf16_t)v0[1]; h[2]=(bf16_t)v0[2]; h[3]=(bf16_t)v0[3];
            h[4]=(bf16_t)v1[0]; h[5]=(bf16_t)v1[1]; h[6]=(bf16_t)v1[2]; h[7]=(bf16_t)v1[3];
            *(bf16x8*)(&As[row * LDPF + a_slot * 8]) = h;
        }
        {
            const int gn = n0 + b_n;
            const float s  = scales[(size_t)g * OUT_F + gn];
            const int   zw = qzeros[(size_t)g * (OUT_F / 8) + (gn >> 3)];
            const float sz = s * (float)(((zw >> ((gn & 7) * 4)) & 0xF) + 1);
            #pragma unroll
            for (int p = 0; p < 2; ++p) {
                const int k8l = b_k8l + p * 2;
                const int w = qweight[(size_t)(k0 / 8 + k8l) * OUT_F + gn];
                bf16x8 h;
                #pragma unroll
                for (int j = 0; j < 8; ++j)
                    h[j] = (bf16_t)fmaf((float)((w >> (4 * j)) & 0xF), s, -sz);
                *(bf16x8*)(&Bs[b_n * LDPF + k8l * 8]) = h;
            }
        }
        __syncthreads();
        bf16x8 af[4], bfr[4];
        #pragma unroll
        for (int m = 0; m < 4; ++m)
            af[m] = *(const bf16x8*)(&As[(wr * 64 + m * 16 + (lane & 15)) * LDPF + (lane >> 4) * 8]);
        #pragma unroll
        for (int n = 0; n < 4; ++n)
            bfr[n] = *(const bf16x8*)(&Bs[(wc * 64 + n * 16 + (lane & 15)) * LDPF + (lane >> 4) * 8]);
        #pragma unroll
        for (int m = 0; m < 4; ++m)
            #pragma unroll
            for (int n = 0; n < 4; ++n)
                acc[m][n] = __builtin_amdgcn_mfma_f32_16x16x32_bf16(af[m], bfr[n], acc[m][n], 0, 0, 0);
    }
    const int cn = lane & 15, cr4 = (lane >> 4) * 4;
    #pragma unroll
    for (int m = 0; m < 4; ++m)
        #pragma unroll
        for (int r = 0; r < 4; ++r) {
            const int grow = m0 + wr * 64 + m * 16 + cr4 + r;
            float* orow = out + (size_t)grow * OUT_F + n0 + wc * 64 + cn;
            #pragma unroll
            for (int n = 0; n < 4; ++n) orow[n * 16] = acc[m][n][r];
        }
}

extern "C" void kernel_launch(void* const* d_in, const int* in_sizes, int n_in,
                              void* d_out, int out_size, void* d_ws, size_t ws_size,
                              hipStream_t stream) {
    const float* x       = (const float*)d_in[0];
    const int*   qweight = (const int*)d_in[1];
    const float* scales  = (const float*)d_in[2];
    const int*   qzeros  = (const int*)d_in[3];
    float* out = (float*)d_out;

    const int M = in_sizes[0] / IN_F;                       // 8192
    const size_t xb_bytes = (size_t)M * IN_F * 2;
    const size_t wt_bytes = (size_t)IN_F * OUT_F * 2;

    if (ws_size >= xb_bytes + wt_bytes && (M % 256) == 0) {
        bf16_t* xb = (bf16_t*)d_ws;
        bf16_t* wt = (bf16_t*)((char*)d_ws + xb_bytes);
        cvt_x_kernel<<<dim3((M * IN_F) / (256 * 8)), dim3(256), 0, stream>>>(x, xb);
        dequant_kernel<<<dim3(OUT_F / 256, IN_F / 32), dim3(256), 0, stream>>>(
            qweight, scales, qzeros, wt);
        const int nwg = (OUT_F / 256) * (M / 256);          // 43*32 = 1376
        gemm_8ph<<<dim3(nwg), dim3(512), 0, stream>>>(xb, wt, out);
    } else {
        gptq_gemm_fused<<<dim3(OUT_F / BNf, M / BMf), dim3(256), 0, stream>>>(
            x, qweight, scales, qzeros, out);
    }
}

// Round 5
// 1281.052 us; speedup vs baseline: 1.0159x; 1.0159x over previous
//
#include <hip/hip_runtime.h>
#include <hip/hip_bf16.h>

#define IN_F 4096
#define OUT_F 11008

typedef __bf16 bf16_t;
typedef bf16_t bf16x8 __attribute__((ext_vector_type(8)));
typedef float f32x4 __attribute__((ext_vector_type(4)));
typedef unsigned int u32;

// ============================ pass 1a: x f32 -> bf16 ============================
__global__ __launch_bounds__(256) void cvt_x_kernel(const float* __restrict__ x,
                                                    bf16_t* __restrict__ xb) {
    size_t i = ((size_t)blockIdx.x * 256 + threadIdx.x) * 8;
    f32x4 v0 = *(const f32x4*)(x + i);
    f32x4 v1 = *(const f32x4*)(x + i + 4);
    bf16x8 h;
    h[0]=(bf16_t)v0[0]; h[1]=(bf16_t)v0[1]; h[2]=(bf16_t)v0[2]; h[3]=(bf16_t)v0[3];
    h[4]=(bf16_t)v1[0]; h[5]=(bf16_t)v1[1]; h[6]=(bf16_t)v1[2]; h[7]=(bf16_t)v1[3];
    *(bf16x8*)(xb + i) = h;
}

// ============ pass 1b: dequant qweight -> Wt[n][k] bf16 (B^T layout) ============
__global__ __launch_bounds__(256) void dequant_kernel(const int* __restrict__ qweight,
                                                      const float* __restrict__ scales,
                                                      const int* __restrict__ qzeros,
                                                      bf16_t* __restrict__ wt) {
    const int n   = blockIdx.x * 256 + threadIdx.x;
    const int kw0 = blockIdx.y * 4;
    const int g   = kw0 >> 4;
    const float s  = scales[(size_t)g * OUT_F + n];
    const int   zw = qzeros[(size_t)g * (OUT_F / 8) + (n >> 3)];
    const float nsz = -s * (float)(((zw >> ((n & 7) * 4)) & 0xF) + 1);
    bf16_t* dst = wt + (size_t)n * IN_F + kw0 * 8;
    #pragma unroll
    for (int j = 0; j < 4; ++j) {
        const int w = qweight[(size_t)(kw0 + j) * OUT_F + n];
        bf16x8 h;
        #pragma unroll
        for (int b = 0; b < 8; ++b)
            h[b] = (bf16_t)fmaf((float)((w >> (4 * b)) & 0xF), s, nsz);
        *(bf16x8*)(dst + j * 8) = h;
    }
}

// ================== pass 2: 256x256 8-phase bf16 B^T GEMM ==================
// R3 schedule (ds_reads pipelined one phase ahead; counted vmcnt at ph3/ph7).
// R4 fix: __launch_bounds__(512, 1) — LDS already caps at 1 block/CU, so the
// (512,2) register cap (128 VGPR) only caused scratch spills of the prefetch
// registers. Freeing the allocator removes the spill traffic.

#define NI (IN_F / 128)   // 32 iterations, 64 K-tiles

__global__ __launch_bounds__(512, 1) void gemm_8ph(const bf16_t* __restrict__ A,
                                                   const bf16_t* __restrict__ B,
                                                   float* __restrict__ C) {
    __shared__ __align__(16) bf16_t smemA[2 * 2 * 128 * 64];   // 64 KiB
    __shared__ __align__(16) bf16_t smemB[2 * 2 * 128 * 64];   // 64 KiB

    const int tid  = threadIdx.x;
    const int lane = tid & 63;
    const int wid  = tid >> 6;      // 0..7
    const int wr   = wid >> 2;      // 0..1  (M half)
    const int wc   = wid & 3;       // 0..3  (N quarter)

    // bijective XCD swizzle: nwg = 1376 = 8*172
    const int bid = blockIdx.x;
    const int swz = (bid & 7) * 172 + (bid >> 3);
    const int bx = swz % 43;
    const int by = swz / 43;
    const int m0 = by * 256;
    const int n0 = bx * 256;

    // staging map: linear LDS slot -> inverse-swizzled global position
    int lr0, kb0, lr1, kb1;
    {
        int L0 = tid * 16;
        int p0 = L0 ^ (((L0 >> 7) & 7) << 4);
        lr0 = p0 >> 7; kb0 = (p0 & 127) >> 1;
        int L1 = (512 + tid) * 16;
        int p1 = L1 ^ (((L1 >> 7) & 7) << 4);
        lr1 = p1 >> 7; kb1 = (p1 & 127) >> 1;
    }

    // fragment-read swizzled column byte offsets within a 128B row
    const int xm = (lane & 7) << 4;
    const int arow = lane & 15;
    int colk[2];
    #pragma unroll
    for (int ks = 0; ks < 2; ++ks)
        colk[ks] = ((ks * 64) + ((lane >> 4) * 16)) ^ xm;

#define STAGE(smem, buf, half, src, rbase, koff)                                           \
    do {                                                                                   \
        const bf16_t* g0_ = (src) + (size_t)((rbase) + lr0) * IN_F + (koff) + kb0;         \
        __builtin_amdgcn_global_load_lds(                                                  \
            (const __attribute__((address_space(1))) u32*)g0_,                             \
            (__attribute__((address_space(3))) u32*)((char*)(smem) + (buf) * 32768 +       \
                                                     (half) * 16384 + wid * 1024),         \
            16, 0, 0);                                                                     \
        const bf16_t* g1_ = (src) + (size_t)((rbase) + lr1) * IN_F + (koff) + kb1;         \
        __builtin_amdgcn_global_load_lds(                                                  \
            (const __attribute__((address_space(1))) u32*)g1_,                             \
            (__attribute__((address_space(3))) u32*)((char*)(smem) + (buf) * 32768 +       \
                                                     (half) * 16384 + 8192 + wid * 1024),  \
            16, 0, 0);                                                                     \
    } while (0)

#define STAGE_A(buf, half, koff) STAGE(smemA, buf, half, A, m0 + (half) * 128, koff)
#define STAGE_B(buf, half, koff) STAGE(smemB, buf, half, B, n0 + (half) * 128, koff)

// 8 ds_read_b128 -> dst[8] : A fragments (4 m-tiles x 2 k-slices)
#define LOAD_A_FRAGS(dst, buf, mbase)                                                      \
    _Pragma("unroll") for (int mm = 0; mm < 4; ++mm)                                       \
    _Pragma("unroll") for (int ks = 0; ks < 2; ++ks)                                       \
        dst[mm * 2 + ks] = *(const bf16x8*)((const char*)smemA + (buf) * 32768 +           \
            wr * 16384 + (((mbase) + mm) * 16 + arow) * 128 + colk[ks]);

// 4 ds_read_b128 -> dst[4] : B pair fragments (2 n-tiles x 2 k-slices), P in {0,1}
#define LOAD_B_PAIR(dst, buf, P)                                                           \
    _Pragma("unroll") for (int nn = 0; nn < 2; ++nn)                                       \
    _Pragma("unroll") for (int ks = 0; ks < 2; ++ks)                                       \
        dst[nn * 2 + ks] = *(const bf16x8*)((const char*)smemB + (buf) * 32768 +           \
            (wc >> 1) * 16384 + ((wc & 1) * 64 + ((P) * 2 + nn) * 16 + arow) * 128 +       \
            colk[ks]);

// 16 MFMA: one quadrant (4 m x 2 n x 2 ks)
#define MFMA_Q(aArr, bArr, mbase, nbase)                                                   \
    __builtin_amdgcn_s_setprio(1);                                                         \
    _Pragma("unroll") for (int mm = 0; mm < 4; ++mm)                                       \
    _Pragma("unroll") for (int nn = 0; nn < 2; ++nn)                                       \
    _Pragma("unroll") for (int ks = 0; ks < 2; ++ks)                                       \
        acc[(mbase) + mm][(nbase) + nn] = __builtin_amdgcn_mfma_f32_16x16x32_bf16(         \
            aArr[mm * 2 + ks], bArr[nn * 2 + ks], acc[(mbase) + mm][(nbase) + nn],         \
            0, 0, 0);                                                                      \
    __builtin_amdgcn_s_setprio(0);

#define BAR() __builtin_amdgcn_s_barrier()
#define VMCNT4() asm volatile("s_waitcnt vmcnt(4)" ::: "memory")
#define VMCNT0() asm volatile("s_waitcnt vmcnt(0)" ::: "memory")

    f32x4 acc[8][4];
    #pragma unroll
    for (int m = 0; m < 8; ++m)
        #pragma unroll
        for (int n = 0; n < 4; ++n)
            acc[m][n] = (f32x4)0.0f;

    bf16x8 aM0[8], aM1[8], b01[4], b23[4];

    // prologue: stage T0 fully + B(T1) + A(T1)h0 (7 half-tiles = 14 loads)
    STAGE_B(0, 0, 0);  STAGE_B(0, 1, 0);
    STAGE_A(0, 0, 0);  STAGE_A(0, 1, 0);
    STAGE_B(1, 0, 64); STAGE_B(1, 1, 64);
    STAGE_A(1, 0, 64);
    asm volatile("s_waitcnt vmcnt(6)" ::: "memory");   // T0's 8 loads landed
    BAR();
    LOAD_A_FRAGS(aM0, 0, 0);       // ph1 fragments (issued one phase ahead)
    LOAD_B_PAIR(b01, 0, 0);

    for (int i = 0; i < NI; ++i) {
        const int  kc = i * 128;        // T0 in buf0; T1 = kc+64 in buf1
        const int  kn = kc + 128;       // T0+2 in buf0; T0+3 = kc+192 in buf1
        const bool nl = (i + 1 < NI);

        // ---- ph1: MFMA(M0,N01,buf0); prefetch b23; stage A-h1(T1)
        LOAD_B_PAIR(b23, 0, 1);
        STAGE_A(1, 1, kc + 64);
        BAR();
        MFMA_Q(aM0, b01, 0, 0);
        BAR();
        // ---- ph2: MFMA(M0,N23); prefetch aM1; stage B-h0(T0+2)
        LOAD_A_FRAGS(aM1, 0, 4);
        if (nl) STAGE_B(0, 0, kn);
        BAR();
        MFMA_Q(aM0, b23, 0, 2);
        BAR();
        // ---- ph3: MFMA(M1,N01); stage B-h1(T0+2); counted wait -> T1 confirmed
        if (nl) STAGE_B(0, 1, kn);
        BAR();
        MFMA_Q(aM1, b01, 4, 0);
        if (nl) VMCNT4(); else VMCNT0();
        BAR();
        // ---- ph4: MFMA(M1,N23); prefetch aM0+b01 (buf1); stage A-h0(T0+2)
        LOAD_A_FRAGS(aM0, 1, 0);
        LOAD_B_PAIR(b01, 1, 0);
        if (nl) STAGE_A(0, 0, kn);
        BAR();
        MFMA_Q(aM1, b23, 4, 2);
        BAR();
        // ---- ph5: MFMA(M0,N01,buf1); prefetch b23; stage A-h1(T0+2)
        LOAD_B_PAIR(b23, 1, 1);
        if (nl) STAGE_A(0, 1, kn);
        BAR();
        MFMA_Q(aM0, b01, 0, 0);
        BAR();
        // ---- ph6: MFMA(M0,N23); prefetch aM1; stage B-h0(T0+3)
        LOAD_A_FRAGS(aM1, 1, 4);
        if (nl) STAGE_B(1, 0, kc + 192);
        BAR();
        MFMA_Q(aM0, b23, 0, 2);
        BAR();
        // ---- ph7: MFMA(M1,N01); stage B-h1(T0+3); counted wait -> T0+2 confirmed
        if (nl) STAGE_B(1, 1, kc + 192);
        BAR();
        MFMA_Q(aM1, b01, 4, 0);
        if (nl) VMCNT4();
        BAR();
        // ---- ph8: MFMA(M1,N23); prefetch aM0+b01 (buf0); stage A-h0(T0+3)
        if (nl) {
            LOAD_A_FRAGS(aM0, 0, 0);
            LOAD_B_PAIR(b01, 0, 0);
            STAGE_A(1, 0, kc + 192);
        }
        BAR();
        MFMA_Q(aM1, b23, 4, 2);
        BAR();
    }

    // epilogue: C/D layout col = lane&15, row = (lane>>4)*4 + r
    const int cn  = lane & 15;
    const int cr4 = (lane >> 4) * 4;
    #pragma unroll
    for (int m = 0; m < 8; ++m) {
        #pragma unroll
        for (int r = 0; r < 4; ++r) {
            const int grow = m0 + wr * 128 + m * 16 + cr4 + r;
            float* orow = C + (size_t)grow * OUT_F + n0 + wc * 64 + cn;
            #pragma unroll
            for (int n = 0; n < 4; ++n)
                orow[n * 16] = acc[m][n][r];
        }
    }
}

// ===================== fallback: fused kernel (R0 structure) =====================
#define BMf 128
#define BNf 128
#define BKf 32
#define LDPF 40

__global__ __launch_bounds__(256, 2) void gptq_gemm_fused(
    const float* __restrict__ x, const int* __restrict__ qweight,
    const float* __restrict__ scales, const int* __restrict__ qzeros,
    float* __restrict__ out)
{
    __shared__ bf16_t As[BMf * LDPF];
    __shared__ bf16_t Bs[BNf * LDPF];
    const int tid = threadIdx.x, lane = tid & 63, wid = tid >> 6;
    const int wr = wid >> 1, wc = wid & 1;
    const int m0 = blockIdx.y * BMf, n0 = blockIdx.x * BNf;
    const int a_row = tid >> 2, a_slot = tid & 3;
    const int b_k8l = tid >> 7, b_n = tid & 127;

    f32x4 acc[4][4];
    #pragma unroll
    for (int i = 0; i < 4; ++i)
        #pragma unroll
        for (int j = 0; j < 4; ++j) acc[i][j] = (f32x4)0.0f;

    for (int kt = 0; kt < IN_F / BKf; ++kt) {
        const int k0 = kt * BKf;
        const int g  = k0 >> 7;
        __syncthreads();
        #pragma unroll
        for (int p = 0; p < 2; ++p) {
            const int row = a_row + p * 64;
            const float* src = x + (size_t)(m0 + row) * IN_F + k0 + a_slot * 8;
            f32x4 v0 = *(const f32x4*)src;
            f32x4 v1 = *(const f32x4*)(src + 4);
            bf16x8 h;
            h[0]=(bf16_t)v0[0]; h[1]=(bf16_t)v0[1]; h[2]=(bf16_t)v0[2]; h[3]=(bf16_t)v0[3];
            h[4]=(bf16_t)v1[0]; h[5]=(bf16_t)v1[1]; h[6]=(bf16_t)v1[2]; h[7]=(bf16_t)v1[3];
            *(bf16x8*)(&As[row * LDPF + a_slot * 8]) = h;
        }
        {
            const int gn = n0 + b_n;
            const float s  = scales[(size_t)g * OUT_F + gn];
            const int   zw = qzeros[(size_t)g * (OUT_F / 8) + (gn >> 3)];
            const float sz = s * (float)(((zw >> ((gn & 7) * 4)) & 0xF) + 1);
            #pragma unroll
            for (int p = 0; p < 2; ++p) {
                const int k8l = b_k8l + p * 2;
                const int w = qweight[(size_t)(k0 / 8 + k8l) * OUT_F + gn];
                bf16x8 h;
                #pragma unroll
                for (int j = 0; j < 8; ++j)
                    h[j] = (bf16_t)fmaf((float)((w >> (4 * j)) & 0xF), s, -sz);
                *(bf16x8*)(&Bs[b_n * LDPF + k8l * 8]) = h;
            }
        }
        __syncthreads();
        bf16x8 af[4], bfr[4];
        #pragma unroll
        for (int m = 0; m < 4; ++m)
            af[m] = *(const bf16x8*)(&As[(wr * 64 + m * 16 + (lane & 15)) * LDPF + (lane >> 4) * 8]);
        #pragma unroll
        for (int n = 0; n < 4; ++n)
            bfr[n] = *(const bf16x8*)(&Bs[(wc * 64 + n * 16 + (lane & 15)) * LDPF + (lane >> 4) * 8]);
        #pragma unroll
        for (int m = 0; m < 4; ++m)
            #pragma unroll
            for (int n = 0; n < 4; ++n)
                acc[m][n] = __builtin_amdgcn_mfma_f32_16x16x32_bf16(af[m], bfr[n], acc[m][n], 0, 0, 0);
    }
    const int cn = lane & 15, cr4 = (lane >> 4) * 4;
    #pragma unroll
    for (int m = 0; m < 4; ++m)
        #pragma unroll
        for (int r = 0; r < 4; ++r) {
            const int grow = m0 + wr * 64 + m * 16 + cr4 + r;
            float* orow = out + (size_t)grow * OUT_F + n0 + wc * 64 + cn;
            #pragma unroll
            for (int n = 0; n < 4; ++n) orow[n * 16] = acc[m][n][r];
        }
}

extern "C" void kernel_launch(void* const* d_in, const int* in_sizes, int n_in,
                              void* d_out, int out_size, void* d_ws, size_t ws_size,
                              hipStream_t stream) {
    const float* x       = (const float*)d_in[0];
    const int*   qweight = (const int*)d_in[1];
    const float* scales  = (const float*)d_in[2];
    const int*   qzeros  = (const int*)d_in[3];
    float* out = (float*)d_out;

    const int M = in_sizes[0] / IN_F;                       // 8192
    const size_t xb_bytes = (size_t)M * IN_F * 2;
    const size_t wt_bytes = (size_t)IN_F * OUT_F * 2;

    if (ws_size >= xb_bytes + wt_bytes && (M % 256) == 0) {
        bf16_t* xb = (bf16_t*)d_ws;
        bf16_t* wt = (bf16_t*)((char*)d_ws + xb_bytes);
        cvt_x_kernel<<<dim3((M * IN_F) / (256 * 8)), dim3(256), 0, stream>>>(x, xb);
        dequant_kernel<<<dim3(OUT_F / 256, IN_F / 32), dim3(256), 0, stream>>>(
            qweight, scales, qzeros, wt);
        const int nwg = (OUT_F / 256) * (M / 256);          // 43*32 = 1376
        gemm_8ph<<<dim3(nwg), dim3(512), 0, stream>>>(xb, wt, out);
    } else {
        gptq_gemm_fused<<<dim3(OUT_F / BNf, M / BMf), dim3(256), 0, stream>>>(
            x, qweight, scales, qzeros, out);
    }
}

// Round 6
// 868.396 us; speedup vs baseline: 1.4987x; 1.4752x over previous
//
#include <hip/hip_runtime.h>
#include <hip/hip_bf16.h>

#define IN_F 4096
#define OUT_F 11008

typedef __bf16 bf16_t;
typedef bf16_t bf16x8 __attribute__((ext_vector_type(8)));
typedef float f32x4 __attribute__((ext_vector_type(4)));
typedef unsigned int u32;

// ============================ pass 1a: x f32 -> bf16 ============================
__global__ __launch_bounds__(256) void cvt_x_kernel(const float* __restrict__ x,
                                                    bf16_t* __restrict__ xb) {
    size_t i = ((size_t)blockIdx.x * 256 + threadIdx.x) * 8;
    f32x4 v0 = *(const f32x4*)(x + i);
    f32x4 v1 = *(const f32x4*)(x + i + 4);
    bf16x8 h;
    h[0]=(bf16_t)v0[0]; h[1]=(bf16_t)v0[1]; h[2]=(bf16_t)v0[2]; h[3]=(bf16_t)v0[3];
    h[4]=(bf16_t)v1[0]; h[5]=(bf16_t)v1[1]; h[6]=(bf16_t)v1[2]; h[7]=(bf16_t)v1[3];
    *(bf16x8*)(xb + i) = h;
}

// ============ pass 1b: dequant qweight -> Wt[n][k] bf16 (B^T layout) ============
__global__ __launch_bounds__(256) void dequant_kernel(const int* __restrict__ qweight,
                                                      const float* __restrict__ scales,
                                                      const int* __restrict__ qzeros,
                                                      bf16_t* __restrict__ wt) {
    const int n   = blockIdx.x * 256 + threadIdx.x;
    const int kw0 = blockIdx.y * 4;
    const int g   = kw0 >> 4;
    const float s  = scales[(size_t)g * OUT_F + n];
    const int   zw = qzeros[(size_t)g * (OUT_F / 8) + (n >> 3)];
    const float nsz = -s * (float)(((zw >> ((n & 7) * 4)) & 0xF) + 1);
    bf16_t* dst = wt + (size_t)n * IN_F + kw0 * 8;
    #pragma unroll
    for (int j = 0; j < 4; ++j) {
        const int w = qweight[(size_t)(kw0 + j) * OUT_F + n];
        bf16x8 h;
        #pragma unroll
        for (int b = 0; b < 8; ++b)
            h[b] = (bf16_t)fmaf((float)((w >> (4 * b)) & 0xF), s, nsz);
        *(bf16x8*)(dst + j * 8) = h;
    }
}

// ================== pass 2: 256x256 8-phase bf16 B^T GEMM ==================
// R5: faithful m201 phase structure — reads issued IN the consuming phase,
// 12/4/8/0 distribution, SHARED A-frag registers (M1 reuses M0's regs),
// B in pairs. Non-acc live ~100 VGPR < 128 cap -> no spill (R3/R4 spilled).
// Explicit lgkmcnt(0)+sched_barrier after barrier (rule #18), lgkmcnt(8)
// pre-drain in 12-read phases, counted vmcnt(6) at ph4/ph8 only.

#define NI (IN_F / 128)   // 32 iterations, 64 K-tiles

__global__ __launch_bounds__(512, 2) void gemm_8ph(const bf16_t* __restrict__ A,
                                                   const bf16_t* __restrict__ B,
                                                   float* __restrict__ C) {
    __shared__ __align__(16) bf16_t smemA[2 * 2 * 128 * 64];   // 64 KiB
    __shared__ __align__(16) bf16_t smemB[2 * 2 * 128 * 64];   // 64 KiB

    const int tid  = threadIdx.x;
    const int lane = tid & 63;
    const int wid  = tid >> 6;      // 0..7
    const int wr   = wid >> 2;      // 0..1  (M half)
    const int wc   = wid & 3;       // 0..3  (N quarter)

    // bijective XCD swizzle: nwg = 1376 = 8*172
    const int bid = blockIdx.x;
    const int swz = (bid & 7) * 172 + (bid >> 3);
    const int bx = swz % 43;
    const int by = swz / 43;
    const int m0 = by * 256;
    const int n0 = bx * 256;

    // staging map: linear LDS slot -> inverse-swizzled global position
    int lr0, kb0, lr1, kb1;
    {
        int L0 = tid * 16;
        int p0 = L0 ^ (((L0 >> 7) & 7) << 4);
        lr0 = p0 >> 7; kb0 = (p0 & 127) >> 1;
        int L1 = (512 + tid) * 16;
        int p1 = L1 ^ (((L1 >> 7) & 7) << 4);
        lr1 = p1 >> 7; kb1 = (p1 & 127) >> 1;
    }

    // fragment-read swizzled column byte offsets within a 128B row
    const int xm = (lane & 7) << 4;
    const int arow = lane & 15;
    int colk[2];
    #pragma unroll
    for (int ks = 0; ks < 2; ++ks)
        colk[ks] = ((ks * 64) + ((lane >> 4) * 16)) ^ xm;

#define STAGE(smem, buf, half, src, rbase, koff)                                           \
    do {                                                                                   \
        const bf16_t* g0_ = (src) + (size_t)((rbase) + lr0) * IN_F + (koff) + kb0;         \
        __builtin_amdgcn_global_load_lds(                                                  \
            (const __attribute__((address_space(1))) u32*)g0_,                             \
            (__attribute__((address_space(3))) u32*)((char*)(smem) + (buf) * 32768 +       \
                                                     (half) * 16384 + wid * 1024),         \
            16, 0, 0);                                                                     \
        const bf16_t* g1_ = (src) + (size_t)((rbase) + lr1) * IN_F + (koff) + kb1;         \
        __builtin_amdgcn_global_load_lds(                                                  \
            (const __attribute__((address_space(1))) u32*)g1_,                             \
            (__attribute__((address_space(3))) u32*)((char*)(smem) + (buf) * 32768 +       \
                                                     (half) * 16384 + 8192 + wid * 1024),  \
            16, 0, 0);                                                                     \
    } while (0)

#define STAGE_A(buf, half, koff) STAGE(smemA, buf, half, A, m0 + (half) * 128, koff)
#define STAGE_B(buf, half, koff) STAGE(smemB, buf, half, B, n0 + (half) * 128, koff)

// 8 ds_read_b128 -> aR[8] : A fragments (4 m-tiles x 2 k-slices)
#define LOAD_A_FRAGS(dst, buf, mbase)                                                      \
    _Pragma("unroll") for (int mm = 0; mm < 4; ++mm)                                       \
    _Pragma("unroll") for (int ks = 0; ks < 2; ++ks)                                       \
        dst[mm * 2 + ks] = *(const bf16x8*)((const char*)smemA + (buf) * 32768 +           \
            wr * 16384 + (((mbase) + mm) * 16 + arow) * 128 + colk[ks]);

// 4 ds_read_b128 -> dst[4] : B pair fragments (2 n-tiles x 2 k-slices), P in {0,1}
#define LOAD_B_PAIR(dst, buf, P)                                                           \
    _Pragma("unroll") for (int nn = 0; nn < 2; ++nn)                                       \
    _Pragma("unroll") for (int ks = 0; ks < 2; ++ks)                                       \
        dst[nn * 2 + ks] = *(const bf16x8*)((const char*)smemB + (buf) * 32768 +           \
            (wc >> 1) * 16384 + ((wc & 1) * 64 + ((P) * 2 + nn) * 16 + arow) * 128 +       \
            colk[ks]);

// 16 MFMA: one quadrant (4 m x 2 n x 2 ks)
#define MFMA_Q(aArr, bArr, mbase, nbase)                                                   \
    __builtin_amdgcn_s_setprio(1);                                                         \
    _Pragma("unroll") for (int mm = 0; mm < 4; ++mm)                                       \
    _Pragma("unroll") for (int nn = 0; nn < 2; ++nn)                                       \
    _Pragma("unroll") for (int ks = 0; ks < 2; ++ks)                                       \
        acc[(mbase) + mm][(nbase) + nn] = __builtin_amdgcn_mfma_f32_16x16x32_bf16(         \
            aArr[mm * 2 + ks], bArr[nn * 2 + ks], acc[(mbase) + mm][(nbase) + nn],         \
            0, 0, 0);                                                                      \
    __builtin_amdgcn_s_setprio(0);

#define BAR() __builtin_amdgcn_s_barrier()
#define LGKM0()                                                                            \
    do {                                                                                   \
        asm volatile("s_waitcnt lgkmcnt(0)" ::: "memory");                                 \
        __builtin_amdgcn_sched_barrier(0);                                                 \
    } while (0)
#define LGKM8() asm volatile("s_waitcnt lgkmcnt(8)" ::: "memory")
#define VMCNT6() asm volatile("s_waitcnt vmcnt(6)" ::: "memory")
#define VMCNT0() asm volatile("s_waitcnt vmcnt(0)" ::: "memory")

    f32x4 acc[8][4];
    #pragma unroll
    for (int m = 0; m < 8; ++m)
        #pragma unroll
        for (int n = 0; n < 4; ++n)
            acc[m][n] = (f32x4)0.0f;

    bf16x8 aR[8], b01[4], b23[4];

    // prologue: stage T0 fully + B(T1) + A(T1)h0 (7 half-tiles = 14 loads)
    STAGE_B(0, 0, 0);  STAGE_B(0, 1, 0);
    STAGE_A(0, 0, 0);  STAGE_A(0, 1, 0);
    STAGE_B(1, 0, 64); STAGE_B(1, 1, 64);
    STAGE_A(1, 0, 64);
    VMCNT6();          // T0's 8 loads landed
    BAR();

    for (int i = 0; i < NI; ++i) {
        const int  kc = i * 128;        // T0 in buf0; T1 = kc+64 in buf1
        const int  kn = kc + 128;       // T0+2 in buf0; T0+3 = kc+192 in buf1
        const bool nl = (i + 1 < NI);

        // ---- ph1: reads aR(M0)+b01 (12); stage A-h1(T1); MFMA(M0,N01,buf0)
        LOAD_A_FRAGS(aR, 0, 0);
        LOAD_B_PAIR(b01, 0, 0);
        STAGE_A(1, 1, kc + 64);
        LGKM8();
        BAR();
        LGKM0();
        MFMA_Q(aR, b01, 0, 0);
        BAR();
        // ---- ph2: reads b23 (4); stage B-h0(T0+2); MFMA(M0,N23)
        LOAD_B_PAIR(b23, 0, 1);
        if (nl) STAGE_B(0, 0, kn);
        BAR();
        LGKM0();
        MFMA_Q(aR, b23, 0, 2);
        BAR();
        // ---- ph3: reads aR(M1) (8, reuses regs); stage B-h1(T0+2); MFMA(M1,N01)
        LOAD_A_FRAGS(aR, 0, 4);
        if (nl) STAGE_B(0, 1, kn);
        BAR();
        LGKM0();
        MFMA_Q(aR, b01, 4, 0);
        BAR();
        // ---- ph4: no reads; stage A-h0(T0+2); MFMA(M1,N23); counted wait -> T1 confirmed
        if (nl) STAGE_A(0, 0, kn);
        BAR();
        MFMA_Q(aR, b23, 4, 2);
        if (nl) VMCNT6(); else VMCNT0();
        BAR();
        // ---- ph5: reads aR(M0)+b01 (12, buf1); stage A-h1(T0+2); MFMA(M0,N01,buf1)
        LOAD_A_FRAGS(aR, 1, 0);
        LOAD_B_PAIR(b01, 1, 0);
        if (nl) STAGE_A(0, 1, kn);
        LGKM8();
        BAR();
        LGKM0();
        MFMA_Q(aR, b01, 0, 0);
        BAR();
        // ---- ph6: reads b23 (4); stage B-h0(T0+3); MFMA(M0,N23)
        LOAD_B_PAIR(b23, 1, 1);
        if (nl) STAGE_B(1, 0, kc + 192);
        BAR();
        LGKM0();
        MFMA_Q(aR, b23, 0, 2);
        BAR();
        // ---- ph7: reads aR(M1) (8); stage B-h1(T0+3); MFMA(M1,N01)
        LOAD_A_FRAGS(aR, 1, 4);
        if (nl) STAGE_B(1, 1, kc + 192);
        BAR();
        LGKM0();
        MFMA_Q(aR, b01, 4, 0);
        BAR();
        // ---- ph8: no reads; stage A-h0(T0+3); MFMA(M1,N23); counted wait -> T0+2 confirmed
        if (nl) STAGE_A(1, 0, kc + 192);
        BAR();
        MFMA_Q(aR, b23, 4, 2);
        if (nl) VMCNT6();
        BAR();
    }

    // epilogue: C/D layout col = lane&15, row = (lane>>4)*4 + r
    const int cn  = lane & 15;
    const int cr4 = (lane >> 4) * 4;
    #pragma unroll
    for (int m = 0; m < 8; ++m) {
        #pragma unroll
        for (int r = 0; r < 4; ++r) {
            const int grow = m0 + wr * 128 + m * 16 + cr4 + r;
            float* orow = C + (size_t)grow * OUT_F + n0 + wc * 64 + cn;
            #pragma unroll
            for (int n = 0; n < 4; ++n)
                orow[n * 16] = acc[m][n][r];
        }
    }
}

// ===================== fallback: fused kernel (R0 structure) =====================
#define BMf 128
#define BNf 128
#define BKf 32
#define LDPF 40

__global__ __launch_bounds__(256, 2) void gptq_gemm_fused(
    const float* __restrict__ x, const int* __restrict__ qweight,
    const float* __restrict__ scales, const int* __restrict__ qzeros,
    float* __restrict__ out)
{
    __shared__ bf16_t As[BMf * LDPF];
    __shared__ bf16_t Bs[BNf * LDPF];
    const int tid = threadIdx.x, lane = tid & 63, wid = tid >> 6;
    const int wr = wid >> 1, wc = wid & 1;
    const int m0 = blockIdx.y * BMf, n0 = blockIdx.x * BNf;
    const int a_row = tid >> 2, a_slot = tid & 3;
    const int b_k8l = tid >> 7, b_n = tid & 127;

    f32x4 acc[4][4];
    #pragma unroll
    for (int i = 0; i < 4; ++i)
        #pragma unroll
        for (int j = 0; j < 4; ++j) acc[i][j] = (f32x4)0.0f;

    for (int kt = 0; kt < IN_F / BKf; ++kt) {
        const int k0 = kt * BKf;
        const int g  = k0 >> 7;
        __syncthreads();
        #pragma unroll
        for (int p = 0; p < 2; ++p) {
            const int row = a_row + p * 64;
            const float* src = x + (size_t)(m0 + row) * IN_F + k0 + a_slot * 8;
            f32x4 v0 = *(const f32x4*)src;
            f32x4 v1 = *(const f32x4*)(src + 4);
            bf16x8 h;
            h[0]=(bf16_t)v0[0]; h[1]=(bf16_t)v0[1]; h[2]=(bf16_t)v0[2]; h[3]=(bf16_t)v0[3];
            h[4]=(bf16_t)v1[0]; h[5]=(bf16_t)v1[1]; h[6]=(bf16_t)v1[2]; h[7]=(bf16_t)v1[3];
            *(bf16x8*)(&As[row * LDPF + a_slot * 8]) = h;
        }
        {
            const int gn = n0 + b_n;
            const float s  = scales[(size_t)g * OUT_F + gn];
            const int   zw = qzeros[(size_t)g * (OUT_F / 8) + (gn >> 3)];
            const float sz = s * (float)(((zw >> ((gn & 7) * 4)) & 0xF) + 1);
            #pragma unroll
            for (int p = 0; p < 2; ++p) {
                const int k8l = b_k8l + p * 2;
                const int w = qweight[(size_t)(k0 / 8 + k8l) * OUT_F + gn];
                bf16x8 h;
                #pragma unroll
                for (int j = 0; j < 8; ++j)
                    h[j] = (bf16_t)fmaf((float)((w >> (4 * j)) & 0xF), s, -sz);
                *(bf16x8*)(&Bs[b_n * LDPF + k8l * 8]) = h;
            }
        }
        __syncthreads();
        bf16x8 af[4], bfr[4];
        #pragma unroll
        for (int m = 0; m < 4; ++m)
            af[m] = *(const bf16x8*)(&As[(wr * 64 + m * 16 + (lane & 15)) * LDPF + (lane >> 4) * 8]);
        #pragma unroll
        for (int n = 0; n < 4; ++n)
            bfr[n] = *(const bf16x8*)(&Bs[(wc * 64 + n * 16 + (lane & 15)) * LDPF + (lane >> 4) * 8]);
        #pragma unroll
        for (int m = 0; m < 4; ++m)
            #pragma unroll
            for (int n = 0; n < 4; ++n)
                acc[m][n] = __builtin_amdgcn_mfma_f32_16x16x32_bf16(af[m], bfr[n], acc[m][n], 0, 0, 0);
    }
    const int cn = lane & 15, cr4 = (lane >> 4) * 4;
    #pragma unroll
    for (int m = 0; m < 4; ++m)
        #pragma unroll
        for (int r = 0; r < 4; ++r) {
            const int grow = m0 + wr * 64 + m * 16 + cr4 + r;
            float* orow = out + (size_t)grow * OUT_F + n0 + wc * 64 + cn;
            #pragma unroll
            for (int n = 0; n < 4; ++n) orow[n * 16] = acc[m][n][r];
        }
}

extern "C" void kernel_launch(void* const* d_in, const int* in_sizes, int n_in,
                              void* d_out, int out_size, void* d_ws, size_t ws_size,
                              hipStream_t stream) {
    const float* x       = (const float*)d_in[0];
    const int*   qweight = (const int*)d_in[1];
    const float* scales  = (const float*)d_in[2];
    const int*   qzeros  = (const int*)d_in[3];
    float* out = (float*)d_out;

    const int M = in_sizes[0] / IN_F;                       // 8192
    const size_t xb_bytes = (size_t)M * IN_F * 2;
    const size_t wt_bytes = (size_t)IN_F * OUT_F * 2;

    if (ws_size >= xb_bytes + wt_bytes && (M % 256) == 0) {
        bf16_t* xb = (bf16_t*)d_ws;
        bf16_t* wt = (bf16_t*)((char*)d_ws + xb_bytes);
        cvt_x_kernel<<<dim3((M * IN_F) / (256 * 8)), dim3(256), 0, stream>>>(x, xb);
        dequant_kernel<<<dim3(OUT_F / 256, IN_F / 32), dim3(256), 0, stream>>>(
            qweight, scales, qzeros, wt);
        const int nwg = (OUT_F / 256) * (M / 256);          // 43*32 = 1376
        gemm_8ph<<<dim3(nwg), dim3(512), 0, stream>>>(xb, wt, out);
    } else {
        gptq_gemm_fused<<<dim3(OUT_F / BNf, M / BMf), dim3(256), 0, stream>>>(
            x, qweight, scales, qzeros, out);
    }
}